// Round 1
// baseline (4352.273 us; speedup 1.0000x reference)
//
#include <hip/hip_runtime.h>

#define D 64

// ---------------- helpers ----------------

__device__ __forceinline__ unsigned int encf(float v) {
    unsigned int u = __float_as_uint(v);
    return (u & 0x80000000u) ? ~u : (u | 0x80000000u);
}
__device__ __forceinline__ float decf(unsigned int e) {
    return __uint_as_float((e & 0x80000000u) ? (e ^ 0x80000000u) : ~e);
}

// ---------------- degree ----------------

__global__ __launch_bounds__(256) void deg_kernel(const int* __restrict__ dst,
                                                  float* __restrict__ deg, int ne) {
    int e = blockIdx.x * blockDim.x + threadIdx.x;
    if (e < ne) atomicAdd(&deg[dst[e]], 1.0f);
}

__global__ __launch_bounds__(256) void inv_deg_kernel(float* __restrict__ deg, int n) {
    int i = blockIdx.x * blockDim.x + threadIdx.x;
    if (i < n) deg[i] = 1.0f / fmaxf(deg[i], 1.0f);
}

// ---------------- SAGE ----------------

// one wave (64 lanes) per edge, lane = feature
__global__ __launch_bounds__(256) void sage_scatter(const float* __restrict__ h,
                                                    const int* __restrict__ src,
                                                    const int* __restrict__ dst,
                                                    float* __restrict__ agg, int ne) {
    int t = blockIdx.x * blockDim.x + threadIdx.x;
    int e = t >> 6, f = t & 63;
    if (e < ne) {
        int s = src[e], d = dst[e];
        atomicAdd(&agg[d * D + f], h[s * D + f]);
    }
}

// out = (agg*inv_deg) @ Wl.T + bl + h @ Wr.T  [+ relu]
__global__ __launch_bounds__(256) void sage_update(const float* __restrict__ h,
                                                   const float* __restrict__ agg,
                                                   const float* __restrict__ inv_deg,
                                                   const float* __restrict__ Wl,
                                                   const float* __restrict__ bl,
                                                   const float* __restrict__ Wr,
                                                   float* __restrict__ out,
                                                   int relu_flag, int n) {
    __shared__ float wl[D][D + 1];
    __shared__ float wr[D][D + 1];
    __shared__ float mrow[4][D];
    __shared__ float hrow[4][D];
    for (int idx = threadIdx.x; idx < D * D; idx += 256) {
        wl[idx >> 6][idx & 63] = Wl[idx];
        wr[idx >> 6][idx & 63] = Wr[idx];
    }
    __syncthreads();
    int nl = threadIdx.x >> 6;   // node slot within block (== wave id)
    int o  = threadIdx.x & 63;   // output feature (== lane)
    int ngroups = (n + 3) >> 2;
    for (int g = blockIdx.x; g < ngroups; g += gridDim.x) {
        int node = g * 4 + nl;
        bool valid = node < n;
        if (valid) {
            float idg = inv_deg[node];
            mrow[nl][o] = agg[node * D + o] * idg;
            hrow[nl][o] = h[node * D + o];
        }
        __syncthreads();
        if (valid) {
            float acc = bl[o];
#pragma unroll
            for (int k = 0; k < D; k++)
                acc += mrow[nl][k] * wl[o][k] + hrow[nl][k] * wr[o][k];
            if (relu_flag) acc = fmaxf(acc, 0.0f);
            out[node * D + o] = acc;
        }
        __syncthreads();
    }
}

// ---------------- GAT ----------------

// ht = h @ W.T ; as = ht . a_src ; ad = ht . a_dst  (per node)
__global__ __launch_bounds__(256) void gat_transform(const float* __restrict__ h,
                                                     const float* __restrict__ W,
                                                     const float* __restrict__ a_src,
                                                     const float* __restrict__ a_dst,
                                                     float* __restrict__ ht,
                                                     float* __restrict__ as_,
                                                     float* __restrict__ ad_, int n) {
    __shared__ float w[D][D + 1];
    __shared__ float hrow[4][D];
    __shared__ float av[2][D];
    for (int idx = threadIdx.x; idx < D * D; idx += 256)
        w[idx >> 6][idx & 63] = W[idx];
    if (threadIdx.x < D) av[0][threadIdx.x] = a_src[threadIdx.x];
    else if (threadIdx.x < 2 * D) av[1][threadIdx.x - D] = a_dst[threadIdx.x - D];
    __syncthreads();
    int nl = threadIdx.x >> 6, o = threadIdx.x & 63;
    int ngroups = (n + 3) >> 2;
    for (int g = blockIdx.x; g < ngroups; g += gridDim.x) {
        int node = g * 4 + nl;
        bool valid = node < n;
        if (valid) hrow[nl][o] = h[node * D + o];
        __syncthreads();
        if (valid) {
            float acc = 0.f;
#pragma unroll
            for (int k = 0; k < D; k++) acc += hrow[nl][k] * w[o][k];
            ht[node * D + o] = acc;
            float s = acc * av[0][o];
            float d = acc * av[1][o];
#pragma unroll
            for (int off = 32; off > 0; off >>= 1) {
                s += __shfl_down(s, off);
                d += __shfl_down(d, off);
            }
            if (o == 0) { as_[node] = s; ad_[node] = d; }
        }
        __syncthreads();
    }
}

__global__ __launch_bounds__(256) void gat_init(unsigned int* __restrict__ m_enc,
                                                float* __restrict__ z, int n) {
    int i = blockIdx.x * blockDim.x + threadIdx.x;
    if (i < n) { m_enc[i] = 0x007FFFFFu; z[i] = 0.f; }  // enc(-inf)
}

// e = leaky_relu(as[s]+ad[d]); segment max via encoded atomicMax
__global__ __launch_bounds__(256) void gat_edge_max(const int* __restrict__ src,
                                                    const int* __restrict__ dst,
                                                    const float* __restrict__ as_,
                                                    const float* __restrict__ ad_,
                                                    float* __restrict__ e_buf,
                                                    unsigned int* __restrict__ m_enc,
                                                    int ne, int n) {
    int eid = blockIdx.x * blockDim.x + threadIdx.x;
    int esl = ne + n;
    if (eid >= esl) return;
    int s, d;
    if (eid < ne) { s = src[eid]; d = dst[eid]; }
    else          { s = d = eid - ne; }
    float x = as_[s] + ad_[d];
    x = (x >= 0.f) ? x : 0.2f * x;
    e_buf[eid] = x;
    atomicMax(&m_enc[d], encf(x));
}

// p = exp(e - m[d]); z[d] += p; e_buf <- p
__global__ __launch_bounds__(256) void gat_edge_sum(const int* __restrict__ dst,
                                                    float* __restrict__ e_buf,
                                                    const unsigned int* __restrict__ m_enc,
                                                    float* __restrict__ z, int ne, int n) {
    int eid = blockIdx.x * blockDim.x + threadIdx.x;
    int esl = ne + n;
    if (eid >= esl) return;
    int d = (eid < ne) ? dst[eid] : eid - ne;
    float p = expf(e_buf[eid] - decf(m_enc[d]));
    e_buf[eid] = p;
    atomicAdd(&z[d], p);
}

// agg[d] += (p/z[d]) * ht[s]  (one wave per edge)
__global__ __launch_bounds__(256) void gat_edge_agg(const int* __restrict__ src,
                                                    const int* __restrict__ dst,
                                                    const float* __restrict__ e_buf,
                                                    const float* __restrict__ z,
                                                    const float* __restrict__ ht,
                                                    float* __restrict__ agg, int ne, int n) {
    int t = blockIdx.x * blockDim.x + threadIdx.x;
    int eid = t >> 6, f = t & 63;
    int esl = ne + n;
    if (eid >= esl) return;
    int s, d;
    if (eid < ne) { s = src[eid]; d = dst[eid]; }
    else          { s = d = eid - ne; }
    float alpha = e_buf[eid] / z[d];
    atomicAdd(&agg[d * D + f], alpha * ht[s * D + f]);
}

__global__ __launch_bounds__(256) void gat_finish(const float* __restrict__ agg,
                                                  const float* __restrict__ b,
                                                  float* __restrict__ out,
                                                  int relu_flag, int n) {
    int t = blockIdx.x * blockDim.x + threadIdx.x;
    if (t < n * D) {
        float v = agg[t] + b[t & 63];
        if (relu_flag) v = fmaxf(v, 0.f);
        out[t] = v;
    }
}

// ---------------- MLP ----------------

__global__ __launch_bounds__(256) void mlp_kernel(const float* __restrict__ h,
                                                  const float* __restrict__ W1,
                                                  const float* __restrict__ b1,
                                                  const float* __restrict__ W2,
                                                  const float* __restrict__ b2,
                                                  const float* __restrict__ W3,
                                                  const float* __restrict__ b3,
                                                  float* __restrict__ out, int n) {
    __shared__ float w1[64][65];
    __shared__ float w2[32][65];
    __shared__ float w3[16][33];
    __shared__ float v0[4][64];
    __shared__ float v1[4][64];
    __shared__ float v2[4][32];
    for (int idx = threadIdx.x; idx < 64 * 64; idx += 256) w1[idx >> 6][idx & 63] = W1[idx];
    for (int idx = threadIdx.x; idx < 32 * 64; idx += 256) w2[idx >> 6][idx & 63] = W2[idx];
    for (int idx = threadIdx.x; idx < 16 * 32; idx += 256) w3[idx >> 5][idx & 31] = W3[idx];
    __syncthreads();
    int nl = threadIdx.x >> 6, o = threadIdx.x & 63;
    int ngroups = (n + 3) >> 2;
    for (int g = blockIdx.x; g < ngroups; g += gridDim.x) {
        int node = g * 4 + nl;
        bool valid = node < n;
        if (valid) v0[nl][o] = h[node * D + o];
        __syncthreads();
        if (valid) {
            float acc = b1[o];
#pragma unroll
            for (int k = 0; k < 64; k++) acc += v0[nl][k] * w1[o][k];
            v1[nl][o] = fmaxf(acc, 0.f);
        }
        __syncthreads();
        if (valid && o < 32) {
            float acc = b2[o];
#pragma unroll
            for (int k = 0; k < 64; k++) acc += v1[nl][k] * w2[o][k];
            v2[nl][o] = fmaxf(acc, 0.f);
        }
        __syncthreads();
        if (valid && o < 16) {
            float acc = b3[o];
#pragma unroll
            for (int k = 0; k < 32; k++) acc += v2[nl][k] * w3[o][k];
            out[node * 16 + o] = acc;
        }
        __syncthreads();
    }
}

// ---------------- launch ----------------

extern "C" void kernel_launch(void* const* d_in, const int* in_sizes, int n_in,
                              void* d_out, int out_size, void* d_ws, size_t ws_size,
                              hipStream_t stream) {
    const int n  = in_sizes[0] / D;      // 100000
    const int ne = in_sizes[1] / 2;      // 1600000
    const int esl = ne + n;

    const float* x        = (const float*)d_in[0];
    const int*   ei       = (const int*)d_in[1];
    const int*   src      = ei;
    const int*   dst      = ei + ne;
    const float* sage_Wl  = (const float*)d_in[2];
    const float* sage_bl  = (const float*)d_in[3];
    const float* sage_Wr  = (const float*)d_in[4];
    const float* gat_W    = (const float*)d_in[5];
    const float* gat_asrc = (const float*)d_in[6];
    const float* gat_adst = (const float*)d_in[7];
    const float* gat_b    = (const float*)d_in[8];
    const float* W1 = (const float*)d_in[9];
    const float* b1 = (const float*)d_in[10];
    const float* W2 = (const float*)d_in[11];
    const float* b2 = (const float*)d_in[12];
    const float* W3 = (const float*)d_in[13];
    const float* b3 = (const float*)d_in[14];
    float* out = (float*)d_out;

    // workspace layout (floats)
    float* deg   = (float*)d_ws;                  // n (becomes inv_deg)
    unsigned int* m_enc = (unsigned int*)(deg + n); // n
    float* z     = (float*)(m_enc + n);           // n
    float* as_   = z + n;                         // n
    float* ad_   = as_ + n;                       // n
    float* e_buf = ad_ + n;                       // ne + n
    float* bufA  = e_buf + esl;                   // n*D
    float* bufB  = bufA + (size_t)n * D;          // n*D
    float* bufC  = bufB + (size_t)n * D;          // n*D (aggregation scratch)

    const int gridN    = (n + 255) / 256;
    const int gridND   = (n * D + 255) / 256;
    const int gridE    = (ne + 255) / 256;
    const int gridESL  = (esl + 255) / 256;
    const int gridE64  = (ne * 64 + 255) / 256;      // ~400k blocks
    const int gridESL64= (esl * 64 + 255) / 256;     // ~425k blocks
    const int MMGRID   = 1024;

    // degrees (SAGE mean), inverted in place
    hipMemsetAsync(deg, 0, (size_t)n * 4, stream);
    deg_kernel<<<gridE, 256, 0, stream>>>(dst, deg, ne);
    inv_deg_kernel<<<gridN, 256, 0, stream>>>(deg, n);

    // ---- 4 SAGE layers (ping-pong x->A->B->A->B) ----
    const float* cur = x;
    float* nxt = bufA;
    for (int l = 0; l < 4; l++) {
        hipMemsetAsync(bufC, 0, (size_t)n * D * 4, stream);
        sage_scatter<<<gridE64, 256, 0, stream>>>(cur, src, dst, bufC, ne);
        sage_update<<<MMGRID, 256, 0, stream>>>(cur, bufC, deg,
                                                sage_Wl + (size_t)l * D * D,
                                                sage_bl + (size_t)l * D,
                                                sage_Wr + (size_t)l * D * D,
                                                nxt, (l < 3) ? 1 : 0, n);
        cur = nxt;
        nxt = (nxt == bufA) ? bufB : bufA;
    }
    // cur == bufB now

    // ---- 4 GAT layers (in-place on bufB, ht in bufA) ----
    float* gin = bufB;
    float* ht  = bufA;
    for (int l = 0; l < 4; l++) {
        gat_transform<<<MMGRID, 256, 0, stream>>>(gin,
                                                  gat_W + (size_t)l * D * D,
                                                  gat_asrc + (size_t)l * D,
                                                  gat_adst + (size_t)l * D,
                                                  ht, as_, ad_, n);
        gat_init<<<gridN, 256, 0, stream>>>(m_enc, z, n);
        gat_edge_max<<<gridESL, 256, 0, stream>>>(src, dst, as_, ad_, e_buf, m_enc, ne, n);
        gat_edge_sum<<<gridESL, 256, 0, stream>>>(dst, e_buf, m_enc, z, ne, n);
        hipMemsetAsync(bufC, 0, (size_t)n * D * 4, stream);
        gat_edge_agg<<<gridESL64, 256, 0, stream>>>(src, dst, e_buf, z, ht, bufC, ne, n);
        gat_finish<<<gridND, 256, 0, stream>>>(bufC, gat_b + (size_t)l * D, gin,
                                               (l < 3) ? 1 : 0, n);
    }

    // ---- projection MLP ----
    mlp_kernel<<<MMGRID, 256, 0, stream>>>(gin, W1, b1, W2, b2, W3, b3, out, n);
}

// Round 2
// 1985.440 us; speedup vs baseline: 2.1921x; 2.1921x over previous
//
#include <hip/hip_runtime.h>

#define D 64

__device__ __forceinline__ float leaky02(float x) {
    return (x >= 0.f) ? x : 0.2f * x;
}

// ---------------- CSR build ----------------

__global__ __launch_bounds__(256) void hist_kernel(const int* __restrict__ dst,
                                                   int* __restrict__ cnt, int ne) {
    int e = blockIdx.x * blockDim.x + threadIdx.x;
    if (e < ne) atomicAdd(&cnt[dst[e]], 1);
}

#define SCAN_BS 256
__global__ __launch_bounds__(SCAN_BS) void scan1_kernel(const int* __restrict__ cnt,
                                                        int* __restrict__ incl,
                                                        int* __restrict__ partials, int n) {
    __shared__ int sm[SCAN_BS];
    int g = blockIdx.x * SCAN_BS + threadIdx.x;
    int v = (g < n) ? cnt[g] : 0;
    sm[threadIdx.x] = v;
    __syncthreads();
    for (int off = 1; off < SCAN_BS; off <<= 1) {
        int t = (threadIdx.x >= off) ? sm[threadIdx.x - off] : 0;
        __syncthreads();
        sm[threadIdx.x] += t;
        __syncthreads();
    }
    if (g < n) incl[g] = sm[threadIdx.x];
    if (threadIdx.x == SCAN_BS - 1) partials[blockIdx.x] = sm[threadIdx.x];
}

__global__ __launch_bounds__(1024) void scan2_kernel(int* __restrict__ partials, int nb) {
    __shared__ int sm[1024];
    int t = threadIdx.x;
    int v = (t < nb) ? partials[t] : 0;
    sm[t] = v;
    __syncthreads();
    for (int off = 1; off < 1024; off <<= 1) {
        int x = (t >= off) ? sm[t - off] : 0;
        __syncthreads();
        sm[t] += x;
        __syncthreads();
    }
    if (t < nb) partials[t] = sm[t] - v;   // exclusive
}

__global__ __launch_bounds__(SCAN_BS) void scan3_kernel(const int* __restrict__ cnt,
                                                        const int* __restrict__ incl,
                                                        const int* __restrict__ partials,
                                                        int* __restrict__ rowptr, int n, int ne) {
    int g = blockIdx.x * SCAN_BS + threadIdx.x;
    if (g < n) rowptr[g] = incl[g] - cnt[g] + partials[blockIdx.x];
    if (g == 0) rowptr[n] = ne;
}

__global__ __launch_bounds__(256) void fill_kernel(const int* __restrict__ src,
                                                   const int* __restrict__ dst,
                                                   const int* __restrict__ rowptr,
                                                   int* __restrict__ fillcnt,
                                                   int* __restrict__ col, int ne) {
    int e = blockIdx.x * blockDim.x + threadIdx.x;
    if (e < ne) {
        int d = dst[e];
        int pos = rowptr[d] + atomicAdd(&fillcnt[d], 1);
        col[pos] = src[e];
    }
}

// ---------------- SAGE fused: gather-mean + dense update ----------------

__global__ __launch_bounds__(256) void sage_fused(const float* __restrict__ h,
                                                  const int* __restrict__ rowptr,
                                                  const int* __restrict__ col,
                                                  const float* __restrict__ Wl,
                                                  const float* __restrict__ bl,
                                                  const float* __restrict__ Wr,
                                                  float* __restrict__ out,
                                                  int relu_flag, int n) {
    __shared__ float wl[D][D + 1];
    __shared__ float wr[D][D + 1];
    __shared__ float rowm[4][D];
    __shared__ float rowh[4][D];
    for (int idx = threadIdx.x; idx < D * D; idx += 256) {
        wl[idx >> 6][idx & 63] = Wl[idx];
        wr[idx >> 6][idx & 63] = Wr[idx];
    }
    __syncthreads();
    int wid = threadIdx.x >> 6, lane = threadIdx.x & 63;
    for (int node = blockIdx.x * 4 + wid; node < n; node += gridDim.x * 4) {
        int start = rowptr[node], end = rowptr[node + 1];
        float acc = 0.f;
        for (int base = start; base < end; base += 64) {
            int idx = base + lane;
            int cnt = min(64, end - base);
            int s_l = (idx < end) ? col[idx] : 0;
            for (int i = 0; i < cnt; i++) {
                int s = __shfl(s_l, i);
                acc += h[(size_t)s * D + lane];
            }
        }
        int deg = end - start;
        float mean = acc / fmaxf((float)deg, 1.f);
        float hv = h[(size_t)node * D + lane];
        // per-wave LDS row broadcast (same-wave DS ops are in-order; no block barrier)
        rowm[wid][lane] = mean;
        rowh[wid][lane] = hv;
        float o = bl[lane];
#pragma unroll
        for (int k = 0; k < D; k++)
            o += rowm[wid][k] * wl[lane][k] + rowh[wid][k] * wr[lane][k];
        if (relu_flag) o = fmaxf(o, 0.f);
        out[(size_t)node * D + lane] = o;
    }
}

// ---------------- GAT ----------------

// ht = h @ W.T ; as = ht . a_src ; ad = ht . a_dst  (per node)
__global__ __launch_bounds__(256) void gat_transform(const float* __restrict__ h,
                                                     const float* __restrict__ W,
                                                     const float* __restrict__ a_src,
                                                     const float* __restrict__ a_dst,
                                                     float* __restrict__ ht,
                                                     float* __restrict__ as_,
                                                     float* __restrict__ ad_, int n) {
    __shared__ float w[D][D + 1];
    __shared__ float hrow[4][D];
    __shared__ float av[2][D];
    for (int idx = threadIdx.x; idx < D * D; idx += 256)
        w[idx >> 6][idx & 63] = W[idx];
    if (threadIdx.x < D) av[0][threadIdx.x] = a_src[threadIdx.x];
    else if (threadIdx.x < 2 * D) av[1][threadIdx.x - D] = a_dst[threadIdx.x - D];
    __syncthreads();
    int wid = threadIdx.x >> 6, o = threadIdx.x & 63;
    for (int node = blockIdx.x * 4 + wid; node < n; node += gridDim.x * 4) {
        hrow[wid][o] = h[(size_t)node * D + o];
        float acc = 0.f;
#pragma unroll
        for (int k = 0; k < D; k++) acc += hrow[wid][k] * w[o][k];
        ht[(size_t)node * D + o] = acc;
        float s = acc * av[0][o];
        float d = acc * av[1][o];
#pragma unroll
        for (int off = 32; off > 0; off >>= 1) {
            s += __shfl_down(s, off);
            d += __shfl_down(d, off);
        }
        if (o == 0) { as_[node] = s; ad_[node] = d; }
    }
}

// fused: per-dst softmax (max, sum) + weighted gather + bias (+relu)
__global__ __launch_bounds__(256) void gat_fused(const int* __restrict__ rowptr,
                                                 const int* __restrict__ col,
                                                 const float* __restrict__ as_,
                                                 const float* __restrict__ ad_,
                                                 const float* __restrict__ ht,
                                                 const float* __restrict__ b,
                                                 float* __restrict__ out,
                                                 int relu_flag, int n) {
    int wid = threadIdx.x >> 6, lane = threadIdx.x & 63;
    for (int node = blockIdx.x * 4 + wid; node < n; node += gridDim.x * 4) {
        int start = rowptr[node], end = rowptr[node + 1];
        float ad_n = ad_[node];
        float e_self = leaky02(as_[node] + ad_n);
        // pass 1: segment max (self-loop included)
        float m = e_self;
        for (int base = start; base < end; base += 64) {
            int idx = base + lane;
            float e = -3.4e38f;
            if (idx < end) e = leaky02(as_[col[idx]] + ad_n);
#pragma unroll
            for (int off = 32; off > 0; off >>= 1)
                e = fmaxf(e, __shfl_xor(e, off));
            m = fmaxf(m, e);
        }
        // pass 2: z and weighted aggregation
        float p_self = __expf(e_self - m);
        float z = p_self;
        float acc = p_self * ht[(size_t)node * D + lane];
        for (int base = start; base < end; base += 64) {
            int idx = base + lane;
            int cnt = min(64, end - base);
            int s_l = (idx < end) ? col[idx] : 0;
            float p_l = (idx < end) ? __expf(leaky02(as_[s_l] + ad_n) - m) : 0.f;
            for (int i = 0; i < cnt; i++) {
                int s = __shfl(s_l, i);
                float p = __shfl(p_l, i);
                z += p;
                acc += p * ht[(size_t)s * D + lane];
            }
        }
        float v = acc / z + b[lane];
        if (relu_flag) v = fmaxf(v, 0.f);
        out[(size_t)node * D + lane] = v;
    }
}

// ---------------- MLP ----------------

__global__ __launch_bounds__(256) void mlp_kernel(const float* __restrict__ h,
                                                  const float* __restrict__ W1,
                                                  const float* __restrict__ b1,
                                                  const float* __restrict__ W2,
                                                  const float* __restrict__ b2,
                                                  const float* __restrict__ W3,
                                                  const float* __restrict__ b3,
                                                  float* __restrict__ out, int n) {
    __shared__ float w1[64][65];
    __shared__ float w2[32][65];
    __shared__ float w3[16][33];
    __shared__ float v0[4][64];
    __shared__ float v1[4][64];
    __shared__ float v2[4][32];
    for (int idx = threadIdx.x; idx < 64 * 64; idx += 256) w1[idx >> 6][idx & 63] = W1[idx];
    for (int idx = threadIdx.x; idx < 32 * 64; idx += 256) w2[idx >> 6][idx & 63] = W2[idx];
    for (int idx = threadIdx.x; idx < 16 * 32; idx += 256) w3[idx >> 5][idx & 31] = W3[idx];
    __syncthreads();
    int nl = threadIdx.x >> 6, o = threadIdx.x & 63;
    int ngroups = (n + 3) >> 2;
    for (int g = blockIdx.x; g < ngroups; g += gridDim.x) {
        int node = g * 4 + nl;
        bool valid = node < n;
        if (valid) v0[nl][o] = h[(size_t)node * D + o];
        __syncthreads();
        if (valid) {
            float acc = b1[o];
#pragma unroll
            for (int k = 0; k < 64; k++) acc += v0[nl][k] * w1[o][k];
            v1[nl][o] = fmaxf(acc, 0.f);
        }
        __syncthreads();
        if (valid && o < 32) {
            float acc = b2[o];
#pragma unroll
            for (int k = 0; k < 64; k++) acc += v1[nl][k] * w2[o][k];
            v2[nl][o] = fmaxf(acc, 0.f);
        }
        __syncthreads();
        if (valid && o < 16) {
            float acc = b3[o];
#pragma unroll
            for (int k = 0; k < 32; k++) acc += v2[nl][k] * w3[o][k];
            out[(size_t)node * 16 + o] = acc;
        }
        __syncthreads();
    }
}

// ---------------- launch ----------------

extern "C" void kernel_launch(void* const* d_in, const int* in_sizes, int n_in,
                              void* d_out, int out_size, void* d_ws, size_t ws_size,
                              hipStream_t stream) {
    const int n  = in_sizes[0] / D;      // 100000
    const int ne = in_sizes[1] / 2;      // 1600000

    const float* x        = (const float*)d_in[0];
    const int*   ei       = (const int*)d_in[1];
    const int*   src      = ei;
    const int*   dst      = ei + ne;
    const float* sage_Wl  = (const float*)d_in[2];
    const float* sage_bl  = (const float*)d_in[3];
    const float* sage_Wr  = (const float*)d_in[4];
    const float* gat_W    = (const float*)d_in[5];
    const float* gat_asrc = (const float*)d_in[6];
    const float* gat_adst = (const float*)d_in[7];
    const float* gat_b    = (const float*)d_in[8];
    const float* W1 = (const float*)d_in[9];
    const float* b1 = (const float*)d_in[10];
    const float* W2 = (const float*)d_in[11];
    const float* b2 = (const float*)d_in[12];
    const float* W3 = (const float*)d_in[13];
    const float* b3 = (const float*)d_in[14];
    float* out = (float*)d_out;

    // workspace layout (4B units)
    int*   cnt      = (int*)d_ws;                    // n (reused as fillcnt)
    int*   incl     = cnt + n;                       // n
    int*   rowptr   = incl + n;                      // n+1
    int*   partials = rowptr + n + 1;                // 1024
    int*   col      = partials + 1024;               // ne
    float* as_      = (float*)(col + ne);            // n
    float* ad_      = as_ + n;                       // n
    float* ht       = ad_ + n;                       // n*D
    float* bufA     = ht + (size_t)n * D;            // n*D
    float* bufB     = bufA + (size_t)n * D;          // n*D

    const int gridN  = (n + 255) / 256;
    const int gridE  = (ne + 255) / 256;
    const int nb     = (n + SCAN_BS - 1) / SCAN_BS;  // 391

    // ---- CSR build ----
    hipMemsetAsync(cnt, 0, (size_t)n * 4, stream);
    hist_kernel<<<gridE, 256, 0, stream>>>(dst, cnt, ne);
    scan1_kernel<<<nb, SCAN_BS, 0, stream>>>(cnt, incl, partials, n);
    scan2_kernel<<<1, 1024, 0, stream>>>(partials, nb);
    scan3_kernel<<<nb, SCAN_BS, 0, stream>>>(cnt, incl, partials, rowptr, n, ne);
    hipMemsetAsync(cnt, 0, (size_t)n * 4, stream);
    fill_kernel<<<gridE, 256, 0, stream>>>(src, dst, rowptr, cnt, col, ne);

    // ---- 4 SAGE layers (x -> A -> B -> A -> B) ----
    const float* cur = x;
    float* nxt = bufA;
    for (int l = 0; l < 4; l++) {
        sage_fused<<<2048, 256, 0, stream>>>(cur, rowptr, col,
                                             sage_Wl + (size_t)l * D * D,
                                             sage_bl + (size_t)l * D,
                                             sage_Wr + (size_t)l * D * D,
                                             nxt, (l < 3) ? 1 : 0, n);
        cur = nxt;
        nxt = (nxt == bufA) ? bufB : bufA;
    }
    // cur == bufB

    // ---- 4 GAT layers (in-place on bufB, ht in its own buffer) ----
    float* gin = bufB;
    for (int l = 0; l < 4; l++) {
        gat_transform<<<2048, 256, 0, stream>>>(gin,
                                                gat_W + (size_t)l * D * D,
                                                gat_asrc + (size_t)l * D,
                                                gat_adst + (size_t)l * D,
                                                ht, as_, ad_, n);
        gat_fused<<<4096, 256, 0, stream>>>(rowptr, col, as_, ad_, ht,
                                            gat_b + (size_t)l * D, gin,
                                            (l < 3) ? 1 : 0, n);
    }

    // ---- projection MLP ----
    mlp_kernel<<<1024, 256, 0, stream>>>(gin, W1, b1, W2, b2, W3, b3, out, n);
}

// Round 3
// 1462.665 us; speedup vs baseline: 2.9756x; 1.3574x over previous
//
#include <hip/hip_runtime.h>

#define D 64
#define D4 16   // D/4 float4 per row

typedef float4 f4;

__device__ __forceinline__ float leaky02(float x) { return (x >= 0.f) ? x : 0.2f * x; }

__device__ __forceinline__ float bcast(float v, int k) {
    return __uint_as_float(__builtin_amdgcn_readlane(__float_as_uint(v), k));
}

__device__ __forceinline__ f4 f4add(f4 a, f4 b) {
    return make_float4(a.x + b.x, a.y + b.y, a.z + b.z, a.w + b.w);
}
__device__ __forceinline__ f4 f4fma(float s, f4 v, f4 a) {
    return make_float4(fmaf(s, v.x, a.x), fmaf(s, v.y, a.y), fmaf(s, v.z, a.z), fmaf(s, v.w, a.w));
}

// ---------------- CSR build ----------------

__global__ __launch_bounds__(256) void hist_kernel(const int* __restrict__ dst,
                                                   int* __restrict__ cnt, int ne) {
    int e = blockIdx.x * blockDim.x + threadIdx.x;
    if (e < ne) atomicAdd(&cnt[dst[e]], 1);
}

#define SCAN_BS 256
__global__ __launch_bounds__(SCAN_BS) void scan1_kernel(const int* __restrict__ cnt,
                                                        int* __restrict__ incl,
                                                        int* __restrict__ partials, int n) {
    __shared__ int sm[SCAN_BS];
    int g = blockIdx.x * SCAN_BS + threadIdx.x;
    int v = (g < n) ? cnt[g] : 0;
    sm[threadIdx.x] = v;
    __syncthreads();
    for (int off = 1; off < SCAN_BS; off <<= 1) {
        int t = (threadIdx.x >= off) ? sm[threadIdx.x - off] : 0;
        __syncthreads();
        sm[threadIdx.x] += t;
        __syncthreads();
    }
    if (g < n) incl[g] = sm[threadIdx.x];
    if (threadIdx.x == SCAN_BS - 1) partials[blockIdx.x] = sm[threadIdx.x];
}

__global__ __launch_bounds__(1024) void scan2_kernel(int* __restrict__ partials, int nb) {
    __shared__ int sm[1024];
    int t = threadIdx.x;
    int v = (t < nb) ? partials[t] : 0;
    sm[t] = v;
    __syncthreads();
    for (int off = 1; off < 1024; off <<= 1) {
        int x = (t >= off) ? sm[t - off] : 0;
        __syncthreads();
        sm[t] += x;
        __syncthreads();
    }
    if (t < nb) partials[t] = sm[t] - v;   // exclusive
}

__global__ __launch_bounds__(SCAN_BS) void scan3_kernel(const int* __restrict__ cnt,
                                                        const int* __restrict__ incl,
                                                        const int* __restrict__ partials,
                                                        int* __restrict__ rowptr, int n, int ne) {
    int g = blockIdx.x * SCAN_BS + threadIdx.x;
    if (g < n) rowptr[g] = incl[g] - cnt[g] + partials[blockIdx.x];
    if (g == 0) rowptr[n] = ne;
}

__global__ __launch_bounds__(256) void fill_kernel(const int* __restrict__ src,
                                                   const int* __restrict__ dst,
                                                   const int* __restrict__ rowptr,
                                                   int* __restrict__ fillcnt,
                                                   int* __restrict__ col, int ne) {
    int e = blockIdx.x * blockDim.x + threadIdx.x;
    if (e < ne) {
        int d = dst[e];
        int pos = rowptr[d] + atomicAdd(&fillcnt[d], 1);
        col[pos] = src[e];
    }
}

// ---------------- SAGE dense: Yl = h@Wl.T ; Zr = h@Wr.T + bl ----------------
// 8 nodes per wave: weights read once from LDS per k, h broadcast via readlane.

__global__ __launch_bounds__(256) void sage_dense(const float* __restrict__ h,
                                                  const float* __restrict__ Wl,
                                                  const float* __restrict__ bl,
                                                  const float* __restrict__ Wr,
                                                  float* __restrict__ Yl,
                                                  float* __restrict__ Zr, int n) {
    __shared__ float wl[D][D + 1];
    __shared__ float wr[D][D + 1];
    for (int idx = threadIdx.x; idx < D * D; idx += 256) {
        wl[idx >> 6][idx & 63] = Wl[idx];
        wr[idx >> 6][idx & 63] = Wr[idx];
    }
    __syncthreads();
    int wid = threadIdx.x >> 6, lane = threadIdx.x & 63;
    float blv = bl[lane];
    int step = gridDim.x * 32;
    for (int nb = (blockIdx.x * 4 + wid) * 8; nb < n; nb += step) {
        int cnt = min(8, n - nb);
        float hv[8];
#pragma unroll
        for (int j = 0; j < 8; j++)
            hv[j] = (j < cnt) ? h[(size_t)(nb + j) * D + lane] : 0.f;
        float accY[8], accZ[8];
#pragma unroll
        for (int j = 0; j < 8; j++) { accY[j] = 0.f; accZ[j] = blv; }
#pragma unroll
        for (int k = 0; k < D; k++) {
            float wlk = wl[lane][k], wrk = wr[lane][k];
#pragma unroll
            for (int j = 0; j < 8; j++) {
                float hk = bcast(hv[j], k);
                accY[j] = fmaf(hk, wlk, accY[j]);
                accZ[j] = fmaf(hk, wrk, accZ[j]);
            }
        }
#pragma unroll
        for (int j = 0; j < 8; j++)
            if (j < cnt) {
                Yl[(size_t)(nb + j) * D + lane] = accY[j];
                Zr[(size_t)(nb + j) * D + lane] = accZ[j];
            }
    }
}

// ---------------- SAGE gather: out = relu(mean_j Yl[j] + Zr[i]) ----------------
// 16 lanes per node (float4), 4 nodes per wave, 4-deep ILP.

__global__ __launch_bounds__(256) void sage_gather(const f4* __restrict__ Yl,
                                                   const f4* __restrict__ Zr,
                                                   const int* __restrict__ rowptr,
                                                   const int* __restrict__ col,
                                                   f4* __restrict__ out,
                                                   int relu_flag, int n) {
    int t = blockIdx.x * 256 + threadIdx.x;
    int l16 = t & 15;
    int gbase = (threadIdx.x & 63) & 48;
    int stride = (gridDim.x * 256) >> 4;
    for (int node = t >> 4; node < n; node += stride) {
        int start = rowptr[node], end = rowptr[node + 1];
        f4 a0 = {0, 0, 0, 0}, a1 = {0, 0, 0, 0}, a2 = {0, 0, 0, 0}, a3 = {0, 0, 0, 0};
        for (int base = start; base < end; base += 16) {
            int idx = base + l16;
            int s_l = (idx < end) ? col[idx] : 0;
            int cnt = min(16, end - base);
            int i = 0;
            for (; i + 3 < cnt; i += 4) {
                int s0 = __shfl(s_l, gbase + i);
                int s1 = __shfl(s_l, gbase + i + 1);
                int s2 = __shfl(s_l, gbase + i + 2);
                int s3 = __shfl(s_l, gbase + i + 3);
                a0 = f4add(a0, Yl[(size_t)s0 * D4 + l16]);
                a1 = f4add(a1, Yl[(size_t)s1 * D4 + l16]);
                a2 = f4add(a2, Yl[(size_t)s2 * D4 + l16]);
                a3 = f4add(a3, Yl[(size_t)s3 * D4 + l16]);
            }
            for (; i < cnt; i++) {
                int s = __shfl(s_l, gbase + i);
                a0 = f4add(a0, Yl[(size_t)s * D4 + l16]);
            }
        }
        f4 a = f4add(f4add(a0, a1), f4add(a2, a3));
        float invd = 1.f / fmaxf((float)(end - start), 1.f);
        f4 z = Zr[(size_t)node * D4 + l16];
        f4 o = make_float4(fmaf(a.x, invd, z.x), fmaf(a.y, invd, z.y),
                           fmaf(a.z, invd, z.z), fmaf(a.w, invd, z.w));
        if (relu_flag) {
            o.x = fmaxf(o.x, 0.f); o.y = fmaxf(o.y, 0.f);
            o.z = fmaxf(o.z, 0.f); o.w = fmaxf(o.w, 0.f);
        }
        out[(size_t)node * D4 + l16] = o;
    }
}

// ---------------- GAT dense: ht = h@W.T ; as = ht.a_src ; ad = ht.a_dst ----------------

__global__ __launch_bounds__(256) void gat_transform(const float* __restrict__ h,
                                                     const float* __restrict__ W,
                                                     const float* __restrict__ a_src,
                                                     const float* __restrict__ a_dst,
                                                     float* __restrict__ ht,
                                                     float* __restrict__ as_,
                                                     float* __restrict__ ad_, int n) {
    __shared__ float w[D][D + 1];
    for (int idx = threadIdx.x; idx < D * D; idx += 256)
        w[idx >> 6][idx & 63] = W[idx];
    __syncthreads();
    int wid = threadIdx.x >> 6, lane = threadIdx.x & 63;
    float a0 = a_src[lane], a1 = a_dst[lane];
    int step = gridDim.x * 32;
    for (int nb = (blockIdx.x * 4 + wid) * 8; nb < n; nb += step) {
        int cnt = min(8, n - nb);
        float hv[8];
#pragma unroll
        for (int j = 0; j < 8; j++)
            hv[j] = (j < cnt) ? h[(size_t)(nb + j) * D + lane] : 0.f;
        float acc[8];
#pragma unroll
        for (int j = 0; j < 8; j++) acc[j] = 0.f;
#pragma unroll
        for (int k = 0; k < D; k++) {
            float wk = w[lane][k];
#pragma unroll
            for (int j = 0; j < 8; j++)
                acc[j] = fmaf(bcast(hv[j], k), wk, acc[j]);
        }
#pragma unroll
        for (int j = 0; j < 8; j++) {
            if (j < cnt) ht[(size_t)(nb + j) * D + lane] = acc[j];
            float s = acc[j] * a0;
            float d = acc[j] * a1;
#pragma unroll
            for (int off = 32; off > 0; off >>= 1) {
                s += __shfl_xor(s, off);
                d += __shfl_xor(d, off);
            }
            if (lane == 0 && j < cnt) { as_[nb + j] = s; ad_[nb + j] = d; }
        }
    }
}

// ---------------- GAT gather: softmax over in-edges + self-loop, weighted agg ----------------

__global__ __launch_bounds__(256) void gat_gather(const int* __restrict__ rowptr,
                                                  const int* __restrict__ col,
                                                  const float* __restrict__ as_,
                                                  const float* __restrict__ ad_,
                                                  const f4* __restrict__ ht,
                                                  const float* __restrict__ b,
                                                  f4* __restrict__ out,
                                                  int relu_flag, int n) {
    int t = blockIdx.x * 256 + threadIdx.x;
    int l16 = t & 15;
    int gbase = (threadIdx.x & 63) & 48;
    int stride = (gridDim.x * 256) >> 4;
    const f4* b4 = (const f4*)b;
    for (int node = t >> 4; node < n; node += stride) {
        int start = rowptr[node], end = rowptr[node + 1];
        float ad_n = ad_[node];
        float e_self = leaky02(as_[node] + ad_n);
        // pass 1: max
        float m = e_self;
        for (int base = start; base < end; base += 16) {
            int idx = base + l16;
            float e = (idx < end) ? leaky02(as_[col[idx]] + ad_n) : -3.4e38f;
#pragma unroll
            for (int off = 8; off > 0; off >>= 1)
                e = fmaxf(e, __shfl_xor(e, off));
            m = fmaxf(m, e);
        }
        // pass 2: z + weighted gather (2-deep ILP)
        float p_self = __expf(e_self - m);
        float z0 = p_self, z1 = 0.f;
        f4 hs = ht[(size_t)node * D4 + l16];
        f4 acc0 = make_float4(p_self * hs.x, p_self * hs.y, p_self * hs.z, p_self * hs.w);
        f4 acc1 = {0, 0, 0, 0};
        for (int base = start; base < end; base += 16) {
            int idx = base + l16;
            int cnt = min(16, end - base);
            int s_l = (idx < end) ? col[idx] : 0;
            float p_l = (idx < end) ? __expf(leaky02(as_[s_l] + ad_n) - m) : 0.f;
            int i = 0;
            for (; i + 1 < cnt; i += 2) {
                int s0 = __shfl(s_l, gbase + i);
                int s1 = __shfl(s_l, gbase + i + 1);
                float p0 = __shfl(p_l, gbase + i);
                float p1 = __shfl(p_l, gbase + i + 1);
                z0 += p0; z1 += p1;
                acc0 = f4fma(p0, ht[(size_t)s0 * D4 + l16], acc0);
                acc1 = f4fma(p1, ht[(size_t)s1 * D4 + l16], acc1);
            }
            if (i < cnt) {
                int s0 = __shfl(s_l, gbase + i);
                float p0 = __shfl(p_l, gbase + i);
                z0 += p0;
                acc0 = f4fma(p0, ht[(size_t)s0 * D4 + l16], acc0);
            }
        }
        float rz = 1.f / (z0 + z1);
        f4 acc = f4add(acc0, acc1);
        f4 bb = b4[l16];
        f4 o = make_float4(fmaf(acc.x, rz, bb.x), fmaf(acc.y, rz, bb.y),
                           fmaf(acc.z, rz, bb.z), fmaf(acc.w, rz, bb.w));
        if (relu_flag) {
            o.x = fmaxf(o.x, 0.f); o.y = fmaxf(o.y, 0.f);
            o.z = fmaxf(o.z, 0.f); o.w = fmaxf(o.w, 0.f);
        }
        out[(size_t)node * D4 + l16] = o;
    }
}

// ---------------- MLP ----------------

__global__ __launch_bounds__(256) void mlp_kernel(const float* __restrict__ h,
                                                  const float* __restrict__ W1,
                                                  const float* __restrict__ b1,
                                                  const float* __restrict__ W2,
                                                  const float* __restrict__ b2,
                                                  const float* __restrict__ W3,
                                                  const float* __restrict__ b3,
                                                  float* __restrict__ out, int n) {
    __shared__ float w1[64][65];
    __shared__ float w2[32][65];
    __shared__ float w3[16][33];
    __shared__ float v0[4][64];
    __shared__ float v1[4][64];
    __shared__ float v2[4][32];
    for (int idx = threadIdx.x; idx < 64 * 64; idx += 256) w1[idx >> 6][idx & 63] = W1[idx];
    for (int idx = threadIdx.x; idx < 32 * 64; idx += 256) w2[idx >> 6][idx & 63] = W2[idx];
    for (int idx = threadIdx.x; idx < 16 * 32; idx += 256) w3[idx >> 5][idx & 31] = W3[idx];
    __syncthreads();
    int nl = threadIdx.x >> 6, o = threadIdx.x & 63;
    int ngroups = (n + 3) >> 2;
    for (int g = blockIdx.x; g < ngroups; g += gridDim.x) {
        int node = g * 4 + nl;
        bool valid = node < n;
        if (valid) v0[nl][o] = h[(size_t)node * D + o];
        __syncthreads();
        if (valid) {
            float acc = b1[o];
#pragma unroll
            for (int k = 0; k < 64; k++) acc += v0[nl][k] * w1[o][k];
            v1[nl][o] = fmaxf(acc, 0.f);
        }
        __syncthreads();
        if (valid && o < 32) {
            float acc = b2[o];
#pragma unroll
            for (int k = 0; k < 64; k++) acc += v1[nl][k] * w2[o][k];
            v2[nl][o] = fmaxf(acc, 0.f);
        }
        __syncthreads();
        if (valid && o < 16) {
            float acc = b3[o];
#pragma unroll
            for (int k = 0; k < 32; k++) acc += v2[nl][k] * w3[o][k];
            out[(size_t)node * 16 + o] = acc;
        }
        __syncthreads();
    }
}

// ---------------- launch ----------------

extern "C" void kernel_launch(void* const* d_in, const int* in_sizes, int n_in,
                              void* d_out, int out_size, void* d_ws, size_t ws_size,
                              hipStream_t stream) {
    const int n  = in_sizes[0] / D;      // 100000
    const int ne = in_sizes[1] / 2;      // 1600000

    const float* x        = (const float*)d_in[0];
    const int*   ei       = (const int*)d_in[1];
    const int*   src      = ei;
    const int*   dst      = ei + ne;
    const float* sage_Wl  = (const float*)d_in[2];
    const float* sage_bl  = (const float*)d_in[3];
    const float* sage_Wr  = (const float*)d_in[4];
    const float* gat_W    = (const float*)d_in[5];
    const float* gat_asrc = (const float*)d_in[6];
    const float* gat_adst = (const float*)d_in[7];
    const float* gat_b    = (const float*)d_in[8];
    const float* W1 = (const float*)d_in[9];
    const float* b1 = (const float*)d_in[10];
    const float* W2 = (const float*)d_in[11];
    const float* b2 = (const float*)d_in[12];
    const float* W3 = (const float*)d_in[13];
    const float* b3 = (const float*)d_in[14];
    float* out = (float*)d_out;

    // workspace layout (4B units, all offsets 16B-aligned)
    int*   cnt      = (int*)d_ws;                    // n
    int*   incl     = cnt + n;                       // n
    int*   rowptr   = incl + n;                      // n+4
    int*   partials = rowptr + n + 4;                // 1024
    int*   col      = partials + 1024;               // ne
    float* as_      = (float*)(col + ne);            // n
    float* ad_      = as_ + n;                       // n
    float* Yl       = ad_ + n;                       // n*D (also GAT ht)
    float* Zr       = Yl + (size_t)n * D;            // n*D
    float* bufA     = Zr + (size_t)n * D;            // n*D
    float* bufB     = bufA + (size_t)n * D;          // n*D

    const int gridE  = (ne + 255) / 256;
    const int nb     = (n + SCAN_BS - 1) / SCAN_BS;
    const int gridG  = (n * 16 + 255) / 256;         // 16 lanes per node

    // ---- CSR build ----
    hipMemsetAsync(cnt, 0, (size_t)n * 4, stream);
    hist_kernel<<<gridE, 256, 0, stream>>>(dst, cnt, ne);
    scan1_kernel<<<nb, SCAN_BS, 0, stream>>>(cnt, incl, partials, n);
    scan2_kernel<<<1, 1024, 0, stream>>>(partials, nb);
    scan3_kernel<<<nb, SCAN_BS, 0, stream>>>(cnt, incl, partials, rowptr, n, ne);
    hipMemsetAsync(cnt, 0, (size_t)n * 4, stream);
    fill_kernel<<<gridE, 256, 0, stream>>>(src, dst, rowptr, cnt, col, ne);

    // ---- 4 SAGE layers (x -> A -> B -> A -> B) ----
    const float* cur = x;
    float* nxt = bufA;
    for (int l = 0; l < 4; l++) {
        sage_dense<<<1024, 256, 0, stream>>>(cur,
                                             sage_Wl + (size_t)l * D * D,
                                             sage_bl + (size_t)l * D,
                                             sage_Wr + (size_t)l * D * D,
                                             Yl, Zr, n);
        sage_gather<<<gridG, 256, 0, stream>>>((const f4*)Yl, (const f4*)Zr,
                                               rowptr, col, (f4*)nxt,
                                               (l < 3) ? 1 : 0, n);
        cur = nxt;
        nxt = (nxt == bufA) ? bufB : bufA;
    }
    // cur == bufB

    // ---- 4 GAT layers (in-place on bufB, ht reuses Yl) ----
    float* gin = bufB;
    for (int l = 0; l < 4; l++) {
        gat_transform<<<1024, 256, 0, stream>>>(gin,
                                                gat_W + (size_t)l * D * D,
                                                gat_asrc + (size_t)l * D,
                                                gat_adst + (size_t)l * D,
                                                Yl, as_, ad_, n);
        gat_gather<<<gridG, 256, 0, stream>>>(rowptr, col, as_, ad_,
                                              (const f4*)Yl,
                                              gat_b + (size_t)l * D, (f4*)gin,
                                              (l < 3) ? 1 : 0, n);
    }

    // ---- projection MLP ----
    mlp_kernel<<<1024, 256, 0, stream>>>(gin, W1, b1, W2, b2, W3, b3, out, n);
}